// Round 2
// baseline (314.388 us; speedup 1.0000x reference)
//
#include <hip/hip_runtime.h>
#include <cstdio>

// Problem constants (from reference): B=32, Cin=128, S=8192, H=4, Hc=32, M=64, Cout=128
#define S_LEN 8192
#define NMODES 64
#define NCOL 128      // 2*NMODES (interleaved re/im columns)
#define NROWS 4096    // B*Cin == B*Cout
#define KSPLIT 8

// ---------------- K0: trig tables ----------------
// T1[s][2m] = cos(2*pi*m*s/S), T1[s][2m+1] = -sin(...)   (forward DFT B-matrix, [8192][128])
// T2[2m][s] = cos(...),        T2[2m+1][s] = -sin(...)   (inverse basis, [128][8192])
__global__ __launch_bounds__(256) void gen_tables(float* __restrict__ T1,
                                                  float* __restrict__ T2) {
    int idx = blockIdx.x * 256 + threadIdx.x;   // 64*8192 total
    int m = idx >> 13;
    int s = idx & (S_LEN - 1);
    int p = (m * s) & (S_LEN - 1);              // exact phase reduction (period S in m*s)
    float ang = (float)p * (6.28318530717958647692f / (float)S_LEN);
    float sn, cs;
    sincosf(ang, &sn, &cs);
    T1[s * NCOL + 2 * m]        = cs;
    T1[s * NCOL + 2 * m + 1]    = -sn;
    T2[(2 * m) * S_LEN + s]     = cs;
    T2[(2 * m + 1) * S_LEN + s] = -sn;
}

// ---------------- K1: forward pruned DFT ----------------
// P[ks][row][col] partial of  C[4096][128] = x[4096][8192] * T1[8192][128]
#define K1_ROWS 64
#define K1_KC 64
__global__ __launch_bounds__(256) void dft_fwd(const float* __restrict__ x,
                                               const float* __restrict__ T1,
                                               float* __restrict__ P) {
    __shared__ float aLds[K1_ROWS][K1_KC];   // [row][k]  16 KB (natural; reads broadcast)
    __shared__ float bLds[K1_KC][NCOL];      // [k][col]  32 KB
    const int rt = blockIdx.x;               // 0..63
    const int ks = blockIdx.y;               // 0..KSPLIT-1
    const int t  = threadIdx.x;
    const int row0  = rt * K1_ROWS;
    const int kbase = ks * (S_LEN / KSPLIT); // 1024-wide K range per block
    const int tr = t >> 5;                   // 0..7  -> rows tr*8..tr*8+7
    const int tc = t & 31;                   // cols tc*4..tc*4+3
    float acc[8][4];
    #pragma unroll
    for (int i = 0; i < 8; ++i)
        #pragma unroll
        for (int j = 0; j < 4; ++j) acc[i][j] = 0.f;

    for (int kc0 = 0; kc0 < S_LEN / KSPLIT; kc0 += K1_KC) {
        // stage A tile [64 rows][64 k] (coalesced float4, natural layout)
        #pragma unroll
        for (int it = 0; it < 4; ++it) {
            int li = t + it * 256;           // 0..1023
            int r  = li >> 4;                // 0..63
            int c4 = li & 15;
            float4 v = *(const float4*)&x[(size_t)(row0 + r) * S_LEN + kbase + kc0 + c4 * 4];
            *(float4*)&aLds[r][c4 * 4] = v;
        }
        // stage B tile [64 k][128 col]
        #pragma unroll
        for (int it = 0; it < 8; ++it) {
            int li = t + it * 256;           // 0..2047
            int kk = li >> 5;
            int c4 = li & 31;
            *(float4*)&bLds[kk][c4 * 4] =
                *(const float4*)&T1[(size_t)(kbase + kc0 + kk) * NCOL + c4 * 4];
        }
        __syncthreads();
        for (int kk = 0; kk < K1_KC; kk += 4) {
            float af[8][4];
            #pragma unroll
            for (int i = 0; i < 8; ++i) {
                float4 a = *(const float4*)&aLds[tr * 8 + i][kk];
                af[i][0] = a.x; af[i][1] = a.y; af[i][2] = a.z; af[i][3] = a.w;
            }
            float bf[4][4];
            #pragma unroll
            for (int u = 0; u < 4; ++u) {
                float4 b = *(const float4*)&bLds[kk + u][tc * 4];
                bf[u][0] = b.x; bf[u][1] = b.y; bf[u][2] = b.z; bf[u][3] = b.w;
            }
            #pragma unroll
            for (int u = 0; u < 4; ++u)
                #pragma unroll
                for (int i = 0; i < 8; ++i)
                    #pragma unroll
                    for (int j = 0; j < 4; ++j)
                        acc[i][j] += af[i][u] * bf[u][j];
        }
        __syncthreads();
    }
    #pragma unroll
    for (int i = 0; i < 8; ++i) {
        float4 v = make_float4(acc[i][0], acc[i][1], acc[i][2], acc[i][3]);
        *(float4*)&P[((size_t)ks * NROWS + row0 + tr * 8 + i) * NCOL + tc * 4] = v;
    }
}

// ---------------- K2: per-mode complex channel contraction ----------------
// X[b,i,m] = sum_ks P ; out[b,h,o,m] = sum_i X[b,i,m]*w[h,i,o,m] (complex)
// C2[row=b*128+h*32+o][2m]   = alpha_m * Re(out)
// C2[row][2m+1]              = alpha_m * Im(out),  alpha_0=1/S else 2/S
__global__ __launch_bounds__(256) void mode_contract(const float* __restrict__ P,
                                                     const float* __restrict__ w_real,
                                                     const float* __restrict__ w_imag,
                                                     float* __restrict__ C2) {
    __shared__ float xr[32][128], xi[32][128];   // 16 KB each
    __shared__ float wr[128][32], wi[128][32];   // 16 KB each (total 64 KB)
    const int m = blockIdx.x;   // 0..63
    const int h = blockIdx.y;   // 0..3
    const int t = threadIdx.x;
    #pragma unroll
    for (int it = 0; it < 16; ++it) {
        int li = t + it * 256;       // 0..4095
        int b = li >> 7, i = li & 127;
        float re = 0.f, im = 0.f;
        #pragma unroll
        for (int ks = 0; ks < KSPLIT; ++ks) {
            const float2 v = *(const float2*)&P[((size_t)ks * NROWS + b * 128 + i) * NCOL + 2 * m];
            re += v.x; im += v.y;
        }
        xr[b][i] = re; xi[b][i] = im;
        int i2 = li >> 5, o = li & 31;
        size_t off = ((size_t)((h * 128 + i2) * 32 + o)) * NMODES + m;
        wr[i2][o] = w_real[off];
        wi[i2][o] = w_imag[off];
    }
    __syncthreads();
    const int o  = t & 31;
    const int b0 = (t >> 5) * 4;
    float re[4] = {0.f, 0.f, 0.f, 0.f}, im[4] = {0.f, 0.f, 0.f, 0.f};
    for (int i = 0; i < 128; ++i) {
        float wrv = wr[i][o], wiv = wi[i][o];
        #pragma unroll
        for (int j = 0; j < 4; ++j) {
            float a = xr[b0 + j][i], c = xi[b0 + j][i];
            re[j] += a * wrv - c * wiv;
            im[j] += a * wiv + c * wrv;
        }
    }
    const float alpha = (m == 0) ? (1.0f / (float)S_LEN) : (2.0f / (float)S_LEN);
    #pragma unroll
    for (int j = 0; j < 4; ++j) {
        int row = (b0 + j) * 128 + h * 32 + o;
        C2[(size_t)row * NCOL + 2 * m]     = alpha * re[j];
        C2[(size_t)row * NCOL + 2 * m + 1] = alpha * im[j];
    }
}

// ---------------- K3: inverse (coeff x basis GEMM) ----------------
// y[4096][8192] = C2[4096][128] * T2[128][8192]
#define K3_ROWS 32
#define K3_COLS 256
#define K3_KC 32
__global__ __launch_bounds__(256) void idft(const float* __restrict__ C2,
                                            const float* __restrict__ T2,
                                            float* __restrict__ y) {
    __shared__ float cLds[K3_ROWS][NCOL];    // 16 KB (all 128 k staged once)
    __shared__ float bLds[K3_KC][K3_COLS];   // 32 KB
    const int ct = blockIdx.x;   // 0..31
    const int rt = blockIdx.y;   // 0..127
    const int t  = threadIdx.x;
    const int row0 = rt * K3_ROWS, col0 = ct * K3_COLS;
    #pragma unroll
    for (int it = 0; it < 4; ++it) {
        int li = t + it * 256;    // 0..1023
        int r = li >> 5, k4 = li & 31;
        *(float4*)&cLds[r][k4 * 4] = *(const float4*)&C2[(size_t)(row0 + r) * NCOL + k4 * 4];
    }
    const int tr = t >> 5;       // rows tr*4..tr*4+3
    const int tc = t & 31;       // cols tc*8..tc*8+7
    float acc[4][8];
    #pragma unroll
    for (int j = 0; j < 4; ++j)
        #pragma unroll
        for (int q = 0; q < 8; ++q) acc[j][q] = 0.f;

    for (int cc = 0; cc < NCOL; cc += K3_KC) {
        __syncthreads();   // also covers cLds staging on first iteration
        #pragma unroll
        for (int it = 0; it < 8; ++it) {
            int li = t + it * 256;     // 0..2047
            int kk = li >> 6, c4 = li & 63;
            *(float4*)&bLds[kk][c4 * 4] =
                *(const float4*)&T2[(size_t)(cc + kk) * S_LEN + col0 + c4 * 4];
        }
        __syncthreads();
        for (int kk = 0; kk < K3_KC; kk += 4) {
            float cf[4][4];
            #pragma unroll
            for (int j = 0; j < 4; ++j) {
                float4 c = *(const float4*)&cLds[tr * 4 + j][cc + kk];
                cf[j][0] = c.x; cf[j][1] = c.y; cf[j][2] = c.z; cf[j][3] = c.w;
            }
            float bf[4][8];
            #pragma unroll
            for (int u = 0; u < 4; ++u) {
                float4 b0v = *(const float4*)&bLds[kk + u][tc * 8];
                float4 b1v = *(const float4*)&bLds[kk + u][tc * 8 + 4];
                bf[u][0] = b0v.x; bf[u][1] = b0v.y; bf[u][2] = b0v.z; bf[u][3] = b0v.w;
                bf[u][4] = b1v.x; bf[u][5] = b1v.y; bf[u][6] = b1v.z; bf[u][7] = b1v.w;
            }
            #pragma unroll
            for (int u = 0; u < 4; ++u)
                #pragma unroll
                for (int j = 0; j < 4; ++j) {
                    float cs = cf[j][u];
                    #pragma unroll
                    for (int q = 0; q < 8; ++q)
                        acc[j][q] += cs * bf[u][q];
                }
        }
    }
    #pragma unroll
    for (int j = 0; j < 4; ++j) {
        size_t base = (size_t)(row0 + tr * 4 + j) * S_LEN + col0 + tc * 8;
        *(float4*)&y[base]     = make_float4(acc[j][0], acc[j][1], acc[j][2], acc[j][3]);
        *(float4*)&y[base + 4] = make_float4(acc[j][4], acc[j][5], acc[j][6], acc[j][7]);
    }
}

extern "C" void kernel_launch(void* const* d_in, const int* in_sizes, int n_in,
                              void* d_out, int out_size, void* d_ws, size_t ws_size,
                              hipStream_t stream) {
    const float* x      = (const float*)d_in[0];
    const float* w_real = (const float*)d_in[1];
    const float* w_imag = (const float*)d_in[2];
    float* y  = (float*)d_out;
    float* ws = (float*)d_ws;

    const size_t T1_OFF = 0;
    const size_t T2_OFF = T1_OFF + (size_t)S_LEN * NCOL;                 // 1 M floats
    const size_t P_OFF  = T2_OFF + (size_t)S_LEN * NCOL;                 // 1 M floats
    const size_t C2_OFF = P_OFF + (size_t)KSPLIT * NROWS * NCOL;         // 4 M floats
    const size_t TOTAL  = C2_OFF + (size_t)NROWS * NCOL;                 // +0.5 M
    if (ws_size < TOTAL * sizeof(float)) {
        fprintf(stderr, "kernel_launch: ws too small (%zu < %zu bytes)\n",
                ws_size, TOTAL * sizeof(float));
        return;
    }
    float* T1 = ws + T1_OFF;
    float* T2 = ws + T2_OFF;
    float* P  = ws + P_OFF;
    float* C2 = ws + C2_OFF;

    gen_tables<<<(NMODES * S_LEN) / 256, 256, 0, stream>>>(T1, T2);
    dft_fwd<<<dim3(NROWS / K1_ROWS, KSPLIT), 256, 0, stream>>>(x, T1, P);
    mode_contract<<<dim3(NMODES, 4), 256, 0, stream>>>(P, w_real, w_imag, C2);
    idft<<<dim3(S_LEN / K3_COLS, NROWS / K3_ROWS), 256, 0, stream>>>(C2, T2, y);
}

// Round 3
// 133.215 us; speedup vs baseline: 2.3600x; 2.3600x over previous
//
#include <hip/hip_runtime.h>
#include <cstdio>

// B=32, Cin=128, S=8192, H=4, Hc=32, M=64, Cout=128
#define S_LEN 8192
#define NM 64
#define KSPLIT 16

typedef short s8v __attribute__((ext_vector_type(8)));   // 8 bf16 (MFMA A/B frag)
typedef short s4v __attribute__((ext_vector_type(4)));
typedef float f4  __attribute__((ext_vector_type(4)));   // MFMA C/D frag

static __device__ inline unsigned short f2bf(float f) {  // RNE fp32->bf16
    unsigned int u = __builtin_bit_cast(unsigned int, f);
    u = (u + 0x7FFFu + ((u >> 16) & 1u)) >> 16;
    return (unsigned short)u;
}
static __device__ inline float bf2f(unsigned short h) {
    unsigned int u = ((unsigned int)h) << 16;
    return __builtin_bit_cast(float, u);
}

// ---------------- table gen ----------------
// T1[s][2m]=cos(2pi m s/S), T1[s][2m+1]=-sin  (K3's B-transposed), bf16 hi/lo
__global__ __launch_bounds__(256) void gen_t1(short* __restrict__ T1h, short* __restrict__ T1l) {
    int idx = blockIdx.x * 256 + threadIdx.x;   // 8192*64
    int s = idx >> 6, m = idx & 63;
    int p = (m * s) & (S_LEN - 1);
    float ang = (float)p * (6.28318530717958647692f / (float)S_LEN);
    float sn, cs; sincosf(ang, &sn, &cs);
    float ms = -sn;
    unsigned short ch = f2bf(cs); float cl = cs - bf2f(ch);
    unsigned short sh = f2bf(ms); float sl = ms - bf2f(sh);
    ((unsigned int*)T1h)[s * 64 + m] = ((unsigned int)sh << 16) | ch;
    ((unsigned int*)T1l)[s * 64 + m] = ((unsigned int)f2bf(sl) << 16) | f2bf(cl);
}
// T2[2m][s]=cos, T2[2m+1][s]=-sin  (K1's B-transposed), bf16 hi/lo
__global__ __launch_bounds__(256) void gen_t2(short* __restrict__ T2h, short* __restrict__ T2l) {
    int idx = blockIdx.x * 256 + threadIdx.x;
    int m = idx >> 13, s = idx & (S_LEN - 1);
    int p = (m * s) & (S_LEN - 1);
    float ang = (float)p * (6.28318530717958647692f / (float)S_LEN);
    float sn, cs; sincosf(ang, &sn, &cs);
    float ms = -sn;
    unsigned short ch = f2bf(cs), sh = f2bf(ms);
    T2h[(size_t)(2 * m) * S_LEN + s]     = (short)ch;
    T2h[(size_t)(2 * m + 1) * S_LEN + s] = (short)sh;
    T2l[(size_t)(2 * m) * S_LEN + s]     = (short)f2bf(cs - bf2f(ch));
    T2l[(size_t)(2 * m + 1) * S_LEN + s] = (short)f2bf(ms - bf2f(sh));
}

// swizzled LDS index (ushort units): tile[r][k], 64 bf16/row (128B), XOR bit-slot
#define SW(r, k) (((r) * 64 + (k)) ^ (((r) & 7) << 3))

// ---------------- K1: X[4096][128] += x[4096][krange] * B1[krange][128], MFMA split-bf16 ----------------
__global__ __launch_bounds__(256, 2) void dft_fwd_mfma(const float* __restrict__ x,
        const short* __restrict__ T2h, const short* __restrict__ T2l,
        float* __restrict__ X) {
    __shared__ short ah[128 * 64], al[128 * 64];   // x tile hi/lo [r][k] swizzled
    __shared__ short bh[128 * 64], bl[128 * 64];   // Bt tile [col][k] swizzled
    const int t = threadIdx.x;
    const int lane = t & 63, wid = t >> 6;
    const int wm = (wid >> 1) * 64, wn = (wid & 1) * 64;
    const int row0 = blockIdx.x * 128;
    const int kbase = blockIdx.y * (S_LEN / KSPLIT);
    f4 acc[4][4];
    #pragma unroll
    for (int i = 0; i < 4; ++i)
        #pragma unroll
        for (int j = 0; j < 4; ++j) acc[i][j] = (f4){0.f, 0.f, 0.f, 0.f};

    for (int kc = 0; kc < S_LEN / KSPLIT; kc += 64) {
        // stage A: 128x64 fp32 -> bf16 hi/lo (reg-staged conversion, swizzled write)
        #pragma unroll
        for (int it = 0; it < 8; ++it) {
            int li = t + it * 256;           // 0..2047
            int r = li >> 4, kq = (li & 15) * 4;
            const float4 v = *(const float4*)&x[(size_t)(row0 + r) * S_LEN + kbase + kc + kq];
            s4v hv, lv;
            { unsigned short h0 = f2bf(v.x); hv[0] = (short)h0; lv[0] = (short)f2bf(v.x - bf2f(h0)); }
            { unsigned short h0 = f2bf(v.y); hv[1] = (short)h0; lv[1] = (short)f2bf(v.y - bf2f(h0)); }
            { unsigned short h0 = f2bf(v.z); hv[2] = (short)h0; lv[2] = (short)f2bf(v.z - bf2f(h0)); }
            { unsigned short h0 = f2bf(v.w); hv[3] = (short)h0; lv[3] = (short)f2bf(v.w - bf2f(h0)); }
            int us = SW(r, kq);
            *(s4v*)&ah[us] = hv;
            *(s4v*)&al[us] = lv;
        }
        // stage B: [128 col][64 k] from T2h/T2l (16B loads, swizzled 16B writes)
        #pragma unroll
        for (int it = 0; it < 4; ++it) {
            int li = t + it * 256;           // 0..1023
            int c = li >> 3, k8 = (li & 7) * 8;
            size_t g = (size_t)c * S_LEN + kbase + kc + k8;
            int us = SW(c, k8);
            *(s8v*)&bh[us] = *(const s8v*)&T2h[g];
            *(s8v*)&bl[us] = *(const s8v*)&T2l[g];
        }
        __syncthreads();
        #pragma unroll
        for (int kf = 0; kf < 2; ++kf) {
            const int kk = kf * 32 + (lane >> 4) * 8;
            s8v Ah[4], Al[4], Bh[4], Bl[4];
            #pragma unroll
            for (int mf = 0; mf < 4; ++mf) {
                int r = wm + mf * 16 + (lane & 15);
                int us = SW(r, kk);
                Ah[mf] = *(const s8v*)&ah[us];
                Al[mf] = *(const s8v*)&al[us];
            }
            #pragma unroll
            for (int nf = 0; nf < 4; ++nf) {
                int c = wn + nf * 16 + (lane & 15);
                int us = SW(c, kk);
                Bh[nf] = *(const s8v*)&bh[us];
                Bl[nf] = *(const s8v*)&bl[us];
            }
            #pragma unroll
            for (int mf = 0; mf < 4; ++mf)
                #pragma unroll
                for (int nf = 0; nf < 4; ++nf) {
                    acc[mf][nf] = __builtin_amdgcn_mfma_f32_16x16x32_bf16(Ah[mf], Bh[nf], acc[mf][nf], 0, 0, 0);
                    acc[mf][nf] = __builtin_amdgcn_mfma_f32_16x16x32_bf16(Al[mf], Bh[nf], acc[mf][nf], 0, 0, 0);
                    acc[mf][nf] = __builtin_amdgcn_mfma_f32_16x16x32_bf16(Ah[mf], Bl[nf], acc[mf][nf], 0, 0, 0);
                }
        }
        __syncthreads();
    }
    // D: row=(lane>>4)*4+reg, col=lane&15 ; cross-KSPLIT reduce via device atomics
    #pragma unroll
    for (int mf = 0; mf < 4; ++mf) {
        int rb = row0 + wm + mf * 16 + (lane >> 4) * 4;
        #pragma unroll
        for (int nf = 0; nf < 4; ++nf) {
            int c = wn + nf * 16 + (lane & 15);
            #pragma unroll
            for (int r = 0; r < 4; ++r)
                atomicAdd(&X[(size_t)(rb + r) * 128 + c], acc[mf][nf][r]);
        }
    }
}

// ---------------- K2: mode contraction, writes C2 as bf16 hi/lo ----------------
__global__ __launch_bounds__(256) void mode_contract(const float* __restrict__ X,
        const float* __restrict__ w_real, const float* __restrict__ w_imag,
        short* __restrict__ C2h, short* __restrict__ C2l) {
    __shared__ float xr[32][128], xi[32][128];
    __shared__ float wr[128][32], wi[128][32];
    const int m = blockIdx.x, h = blockIdx.y, t = threadIdx.x;
    #pragma unroll
    for (int it = 0; it < 16; ++it) {
        int li = t + it * 256;       // 0..4095
        int b = li >> 7, i = li & 127;
        const float2 v = *(const float2*)&X[(size_t)(b * 128 + i) * 128 + 2 * m];
        xr[b][i] = v.x; xi[b][i] = v.y;
        int i2 = li >> 5, o = li & 31;
        size_t off = ((size_t)((h * 128 + i2) * 32 + o)) * NM + m;
        wr[i2][o] = w_real[off];
        wi[i2][o] = w_imag[off];
    }
    __syncthreads();
    const int o = t & 31;
    const int b0 = (t >> 5) * 4;
    float re[4] = {0.f, 0.f, 0.f, 0.f}, im[4] = {0.f, 0.f, 0.f, 0.f};
    for (int i = 0; i < 128; ++i) {
        float wrv = wr[i][o], wiv = wi[i][o];
        #pragma unroll
        for (int j = 0; j < 4; ++j) {
            float a = xr[b0 + j][i], c = xi[b0 + j][i];
            re[j] += a * wrv - c * wiv;
            im[j] += a * wiv + c * wrv;
        }
    }
    const float alpha = (m == 0) ? (1.0f / (float)S_LEN) : (2.0f / (float)S_LEN);
    #pragma unroll
    for (int j = 0; j < 4; ++j) {
        int row = (b0 + j) * 128 + h * 32 + o;
        float vr = alpha * re[j], vi = alpha * im[j];
        unsigned short hr = f2bf(vr), hi_ = f2bf(vi);
        float lr = vr - bf2f(hr), li_ = vi - bf2f(hi_);
        ((unsigned int*)C2h)[(size_t)row * 64 + m] = ((unsigned int)hi_ << 16) | hr;
        ((unsigned int*)C2l)[(size_t)row * 64 + m] = ((unsigned int)f2bf(li_) << 16) | f2bf(lr);
    }
}

// ---------------- K3: y[4096][8192] = C2[4096][128] * Basis[128][8192], MFMA split-bf16 ----------------
__global__ __launch_bounds__(256, 2) void idft_mfma(const short* __restrict__ C2h,
        const short* __restrict__ C2l, const short* __restrict__ T1h,
        const short* __restrict__ T1l, float* __restrict__ y) {
    __shared__ short ah[128 * 64], al[128 * 64];   // C2 tile [r][k]
    __shared__ short bh[128 * 64], bl[128 * 64];   // Basis^T tile [s][k] (=T1 rows)
    const int t = threadIdx.x;
    const int lane = t & 63, wid = t >> 6;
    const int wm = (wid >> 1) * 64, wn = (wid & 1) * 64;
    const int row0 = blockIdx.y * 128, col0 = blockIdx.x * 128;
    f4 acc[4][4];
    #pragma unroll
    for (int i = 0; i < 4; ++i)
        #pragma unroll
        for (int j = 0; j < 4; ++j) acc[i][j] = (f4){0.f, 0.f, 0.f, 0.f};

    #pragma unroll
    for (int kc = 0; kc < 128; kc += 64) {
        #pragma unroll
        for (int it = 0; it < 4; ++it) {
            int li = t + it * 256;           // 0..1023
            int r = li >> 3, k8 = (li & 7) * 8;
            int us = SW(r, k8);
            *(s8v*)&ah[us] = *(const s8v*)&C2h[(size_t)(row0 + r) * 128 + kc + k8];
            *(s8v*)&al[us] = *(const s8v*)&C2l[(size_t)(row0 + r) * 128 + kc + k8];
            *(s8v*)&bh[us] = *(const s8v*)&T1h[(size_t)(col0 + r) * 128 + kc + k8];
            *(s8v*)&bl[us] = *(const s8v*)&T1l[(size_t)(col0 + r) * 128 + kc + k8];
        }
        __syncthreads();
        #pragma unroll
        for (int kf = 0; kf < 2; ++kf) {
            const int kk = kf * 32 + (lane >> 4) * 8;
            s8v Ah[4], Al[4], Bh[4], Bl[4];
            #pragma unroll
            for (int mf = 0; mf < 4; ++mf) {
                int r = wm + mf * 16 + (lane & 15);
                int us = SW(r, kk);
                Ah[mf] = *(const s8v*)&ah[us];
                Al[mf] = *(const s8v*)&al[us];
            }
            #pragma unroll
            for (int nf = 0; nf < 4; ++nf) {
                int c = wn + nf * 16 + (lane & 15);
                int us = SW(c, kk);
                Bh[nf] = *(const s8v*)&bh[us];
                Bl[nf] = *(const s8v*)&bl[us];
            }
            #pragma unroll
            for (int mf = 0; mf < 4; ++mf)
                #pragma unroll
                for (int nf = 0; nf < 4; ++nf) {
                    acc[mf][nf] = __builtin_amdgcn_mfma_f32_16x16x32_bf16(Ah[mf], Bh[nf], acc[mf][nf], 0, 0, 0);
                    acc[mf][nf] = __builtin_amdgcn_mfma_f32_16x16x32_bf16(Al[mf], Bh[nf], acc[mf][nf], 0, 0, 0);
                    acc[mf][nf] = __builtin_amdgcn_mfma_f32_16x16x32_bf16(Ah[mf], Bl[nf], acc[mf][nf], 0, 0, 0);
                }
        }
        __syncthreads();
    }
    #pragma unroll
    for (int mf = 0; mf < 4; ++mf) {
        int rb = row0 + wm + mf * 16 + (lane >> 4) * 4;
        #pragma unroll
        for (int nf = 0; nf < 4; ++nf) {
            int c = col0 + wn + nf * 16 + (lane & 15);
            #pragma unroll
            for (int r = 0; r < 4; ++r)
                y[(size_t)(rb + r) * S_LEN + c] = acc[mf][nf][r];
        }
    }
}

extern "C" void kernel_launch(void* const* d_in, const int* in_sizes, int n_in,
                              void* d_out, int out_size, void* d_ws, size_t ws_size,
                              hipStream_t stream) {
    const float* x      = (const float*)d_in[0];
    const float* w_real = (const float*)d_in[1];
    const float* w_imag = (const float*)d_in[2];
    float* y = (float*)d_out;

    // ws layout (ushort/float units): 4 trig tables (2MB each) + X (2MB) + C2 hi/lo (1MB each)
    const size_t TBL = (size_t)S_LEN * 128;             // 1M elems per table
    char* w0 = (char*)d_ws;
    short* T1h = (short*)w0;
    short* T1l = T1h + TBL;
    short* T2h = T1l + TBL;
    short* T2l = T2h + TBL;
    float* X   = (float*)(T2l + TBL);                   // 4096*128 fp32
    short* C2h = (short*)(X + (size_t)4096 * 128);
    short* C2l = C2h + (size_t)4096 * 128;
    const size_t TOTAL = (size_t)((char*)(C2l + (size_t)4096 * 128) - w0);
    if (ws_size < TOTAL) {
        fprintf(stderr, "kernel_launch: ws too small (%zu < %zu bytes)\n", ws_size, TOTAL);
        return;
    }

    hipMemsetAsync(X, 0, (size_t)4096 * 128 * sizeof(float), stream);
    gen_t1<<<(S_LEN * 64) / 256, 256, 0, stream>>>(T1h, T1l);
    gen_t2<<<(S_LEN * 64) / 256, 256, 0, stream>>>(T2h, T2l);
    dft_fwd_mfma<<<dim3(4096 / 128, KSPLIT), 256, 0, stream>>>(x, T2h, T2l, X);
    mode_contract<<<dim3(NM, 4), 256, 0, stream>>>(X, w_real, w_imag, C2h, C2l);
    idft_mfma<<<dim3(S_LEN / 128, 4096 / 128), 256, 0, stream>>>(C2h, C2l, T1h, T1l, y);
}

// Round 4
// 133.089 us; speedup vs baseline: 2.3622x; 1.0009x over previous
//
#include <hip/hip_runtime.h>
#include <cstdio>

// B=32, Cin=128, S=8192, H=4, Hc=32, M=64, Cout=128
#define S_LEN 8192
#define NM 64
#define KSPLIT 16            // K1 k-split: 512 K per block
#define BK 32                // K-step for both MFMA GEMMs

typedef short s8v __attribute__((ext_vector_type(8)));   // 8 bf16 (MFMA A/B frag)
typedef short s4v __attribute__((ext_vector_type(4)));
typedef float f4  __attribute__((ext_vector_type(4)));   // MFMA C/D frag

static __device__ inline unsigned short f2bf(float f) {  // RNE fp32->bf16
    unsigned int u = __builtin_bit_cast(unsigned int, f);
    u = (u + 0x7FFFu + ((u >> 16) & 1u)) >> 16;
    return (unsigned short)u;
}
static __device__ inline float bf2f(unsigned short h) {
    unsigned int u = ((unsigned int)h) << 16;
    return __builtin_bit_cast(float, u);
}

// Swizzled index (ushort units) within a [128 r][32 k] bf16 tile (64 B rows).
// XOR k-bits 3..4 with (r>>1)&3 -> 16 rows x 4 slots all distinct per wave quarter,
// 2-way bank aliasing max (free, m136). Involution (self-inverse).
#define SW32(r, k) (((r) * 32) + ((k) ^ ((((r) >> 1) & 3) << 3)))

// global->LDS DMA, 16B per lane. dst: wave-uniform LDS base (HW adds lane*16);
// src: per-lane global address.
static __device__ __forceinline__ void glds16(const void* g, void* l) {
    __builtin_amdgcn_global_load_lds(
        (const __attribute__((address_space(1))) unsigned int*)g,
        (__attribute__((address_space(3))) unsigned int*)l, 16, 0, 0);
}

// ---------------- table gen (pre-swizzled tile images) ----------------
// T2 image: K1's B^T. Element (c,kg): c in [0,128) = 2m|2m+1 (re/im col), kg in [0,8192).
// value = (c&1) ? -sin(2pi m kg/S) : cos(2pi m kg/S). Tile = kg-slice of 32,
// layout: img[ktile*4096 + SW32(c, kg&31)], ktile in [0,256).
__global__ __launch_bounds__(256) void gen_t2_img(short* __restrict__ Th,
                                                  short* __restrict__ Tl) {
    int tid = blockIdx.x * 256 + threadIdx.x;     // 1M = 256 tiles * 4096
    int ktile = tid >> 12;
    int us = tid & 4095;
    int c = us >> 5, kx = us & 31;
    int lk = kx ^ (((c >> 1) & 3) << 3);          // invert swizzle
    int kg = ktile * 32 + lk;
    int m = c >> 1;
    int p = (m * kg) & (S_LEN - 1);
    float ang = (float)p * (6.28318530717958647692f / (float)S_LEN);
    float sn, cs; sincosf(ang, &sn, &cs);
    float v = (c & 1) ? -sn : cs;
    unsigned short h = f2bf(v);
    Th[tid] = (short)h;
    Tl[tid] = (short)f2bf(v - bf2f(h));
}

// T1 image: K3's B^T. Element (s,k): s in [0,8192) output col, k in [0,128) = 2m|2m+1.
// Tile = (s-block of 128, k-slice of 32): img[(sb*4+kc)*4096 + SW32(s&127, k&31)].
__global__ __launch_bounds__(256) void gen_t1_img(short* __restrict__ Th,
                                                  short* __restrict__ Tl) {
    int tid = blockIdx.x * 256 + threadIdx.x;     // 1M = 256 tiles * 4096
    int tile = tid >> 12;
    int sb = tile >> 2, kc = tile & 3;
    int us = tid & 4095;
    int ls = us >> 5, kx = us & 31;
    int lk = kx ^ (((ls >> 1) & 3) << 3);
    int s = sb * 128 + ls;
    int k = kc * 32 + lk;
    int m = k >> 1;
    int p = (m * s) & (S_LEN - 1);
    float ang = (float)p * (6.28318530717958647692f / (float)S_LEN);
    float sn, cs; sincosf(ang, &sn, &cs);
    float v = (k & 1) ? -sn : cs;                 // k=1 (Im of DC) -> -sin(0)=0: irfft drops Im(DC)
    unsigned short h = f2bf(v);
    Th[tid] = (short)h;
    Tl[tid] = (short)f2bf(v - bf2f(h));
}

// ---------------- K1: X[4096][128] += x[4096][kslice] * B1[kslice][128] ----------------
// split-bf16 3-pass MFMA; A reg-staged (fp32->hi/lo), B via global_load_lds from image.
__global__ __launch_bounds__(256, 3) void dft_fwd_mfma(const float* __restrict__ x,
        const short* __restrict__ T2h, const short* __restrict__ T2l,
        float* __restrict__ X) {
    __shared__ short ah[128 * BK], al[128 * BK];   // 8 KB each
    __shared__ short bh[128 * BK], bl[128 * BK];
    const int t = threadIdx.x;
    const int lane = t & 63, wid = t >> 6;
    const int wm = (wid >> 1) * 64, wn = (wid & 1) * 64;
    const int row0 = blockIdx.x * 128;
    const int ks = blockIdx.y;
    const int kbase = ks * (S_LEN / KSPLIT);
    f4 acc[4][4];
    #pragma unroll
    for (int i = 0; i < 4; ++i)
        #pragma unroll
        for (int j = 0; j < 4; ++j) acc[i][j] = (f4){0.f, 0.f, 0.f, 0.f};

    for (int kc = 0; kc < (S_LEN / KSPLIT) / BK; ++kc) {
        // ---- A global loads FIRST (conversion can start at vmcnt(8), B-DMA still in flight)
        float4 av[4];
        #pragma unroll
        for (int it = 0; it < 4; ++it) {
            int li = t + it * 256;               // 0..1023
            int r = li >> 3, k4 = (li & 7) * 4;  // 8 threads cover a full 128B row-span
            av[it] = *(const float4*)&x[(size_t)(row0 + r) * S_LEN + kbase + kc * BK + k4];
        }
        // ---- B via DMA from pre-swizzled image (linear dest == swizzled layout)
        {
            const int ktile = ks * ((S_LEN / KSPLIT) / BK) + kc;
            const size_t tb = (size_t)ktile * 8192;       // bytes per tile image
            const int wo = wid * 2048 + lane * 16;
            glds16((const char*)T2h + tb + wo,        (char*)bh + wid * 2048);
            glds16((const char*)T2h + tb + wo + 1024, (char*)bh + wid * 2048 + 1024);
            glds16((const char*)T2l + tb + wo,        (char*)bl + wid * 2048);
            glds16((const char*)T2l + tb + wo + 1024, (char*)bl + wid * 2048 + 1024);
        }
        // ---- convert A -> bf16 hi/lo, swizzled ds_write (overlaps B-DMA latency)
        #pragma unroll
        for (int it = 0; it < 4; ++it) {
            int li = t + it * 256;
            int r = li >> 3, k4 = (li & 7) * 4;
            s4v hv, lv;
            { unsigned short h = f2bf(av[it].x); hv[0] = (short)h; lv[0] = (short)f2bf(av[it].x - bf2f(h)); }
            { unsigned short h = f2bf(av[it].y); hv[1] = (short)h; lv[1] = (short)f2bf(av[it].y - bf2f(h)); }
            { unsigned short h = f2bf(av[it].z); hv[2] = (short)h; lv[2] = (short)f2bf(av[it].z - bf2f(h)); }
            { unsigned short h = f2bf(av[it].w); hv[3] = (short)h; lv[3] = (short)f2bf(av[it].w - bf2f(h)); }
            int us = SW32(r, k4);
            *(s4v*)&ah[us] = hv;
            *(s4v*)&al[us] = lv;
        }
        __syncthreads();
        // ---- MFMA: one 16x16x32 per (mf,nf) per pass
        {
            const int kk = (lane >> 4) * 8;
            s8v Bh[4], Bl[4];
            #pragma unroll
            for (int nf = 0; nf < 4; ++nf) {
                int us = SW32(wn + nf * 16 + (lane & 15), kk);
                Bh[nf] = *(const s8v*)&bh[us];
                Bl[nf] = *(const s8v*)&bl[us];
            }
            #pragma unroll
            for (int mf = 0; mf < 4; ++mf) {
                int us = SW32(wm + mf * 16 + (lane & 15), kk);
                s8v Ah = *(const s8v*)&ah[us];
                s8v Al = *(const s8v*)&al[us];
                #pragma unroll
                for (int nf = 0; nf < 4; ++nf) {
                    acc[mf][nf] = __builtin_amdgcn_mfma_f32_16x16x32_bf16(Ah, Bh[nf], acc[mf][nf], 0, 0, 0);
                    acc[mf][nf] = __builtin_amdgcn_mfma_f32_16x16x32_bf16(Al, Bh[nf], acc[mf][nf], 0, 0, 0);
                    acc[mf][nf] = __builtin_amdgcn_mfma_f32_16x16x32_bf16(Ah, Bl[nf], acc[mf][nf], 0, 0, 0);
                }
            }
        }
        __syncthreads();
    }
    // D: row=(lane>>4)*4+reg, col=lane&15 ; cross-KSPLIT reduce via device atomics
    #pragma unroll
    for (int mf = 0; mf < 4; ++mf) {
        int rb = row0 + wm + mf * 16 + (lane >> 4) * 4;
        #pragma unroll
        for (int nf = 0; nf < 4; ++nf) {
            int c = wn + nf * 16 + (lane & 15);
            #pragma unroll
            for (int r = 0; r < 4; ++r)
                atomicAdd(&X[(size_t)(rb + r) * 128 + c], acc[mf][nf][r]);
        }
    }
}

// ---------------- K2: mode contraction -> C2 image (pre-swizzled bf16 hi/lo) ----------------
__global__ __launch_bounds__(256) void mode_contract(const float* __restrict__ X,
        const float* __restrict__ w_real, const float* __restrict__ w_imag,
        short* __restrict__ C2h, short* __restrict__ C2l) {
    __shared__ float xr[32][128], xi[32][128];
    __shared__ float wr[128][32], wi[128][32];
    const int m = blockIdx.x, h = blockIdx.y, t = threadIdx.x;
    #pragma unroll
    for (int it = 0; it < 16; ++it) {
        int li = t + it * 256;       // 0..4095
        int b = li >> 7, i = li & 127;
        const float2 v = *(const float2*)&X[(size_t)(b * 128 + i) * 128 + 2 * m];
        xr[b][i] = v.x; xi[b][i] = v.y;
        int i2 = li >> 5, o = li & 31;
        size_t off = ((size_t)((h * 128 + i2) * 32 + o)) * NM + m;
        wr[i2][o] = w_real[off];
        wi[i2][o] = w_imag[off];
    }
    __syncthreads();
    const int o = t & 31;
    const int b0 = (t >> 5) * 4;
    float re[4] = {0.f, 0.f, 0.f, 0.f}, im[4] = {0.f, 0.f, 0.f, 0.f};
    for (int i = 0; i < 128; ++i) {
        float wrv = wr[i][o], wiv = wi[i][o];
        #pragma unroll
        for (int j = 0; j < 4; ++j) {
            float a = xr[b0 + j][i], c = xi[b0 + j][i];
            re[j] += a * wrv - c * wiv;
            im[j] += a * wiv + c * wrv;
        }
    }
    const float alpha = (m == 0) ? (1.0f / (float)S_LEN) : (2.0f / (float)S_LEN);
    // C2 image for K3's A: tile (rb=row>>7, kc=k>>5), us=SW32(row&127, k&31), k=2m|2m+1.
    const int kc = m >> 4;
    const int lk = (2 * m) & 31;     // even; SW32 XOR (bits 3..4) keeps pair adjacency+alignment
    #pragma unroll
    for (int j = 0; j < 4; ++j) {
        int row = (b0 + j) * 128 + h * 32 + o;
        float vr = alpha * re[j], vi = alpha * im[j];
        unsigned short hr = f2bf(vr), hi_ = f2bf(vi);
        float lr = vr - bf2f(hr), li_ = vi - bf2f(hi_);
        int rb = row >> 7, lr_ = row & 127;
        size_t ui = ((size_t)(rb * 4 + kc) * 4096 + SW32(lr_, lk)) >> 1;   // uint index
        ((unsigned int*)C2h)[ui] = ((unsigned int)hi_ << 16) | hr;
        ((unsigned int*)C2l)[ui] = ((unsigned int)f2bf(li_) << 16) | f2bf(lr);
    }
}

// ---------------- K3: y[4096][8192] = C2[4096][128] * Basis[128][8192] ----------------
// ALL staging via global_load_lds from pre-swizzled images; zero staging VALU.
__global__ __launch_bounds__(256, 3) void idft_mfma(const short* __restrict__ C2h,
        const short* __restrict__ C2l, const short* __restrict__ T1h,
        const short* __restrict__ T1l, float* __restrict__ y) {
    __shared__ short ah[128 * BK], al[128 * BK];
    __shared__ short bh[128 * BK], bl[128 * BK];
    const int t = threadIdx.x;
    const int lane = t & 63, wid = t >> 6;
    const int wm = (wid >> 1) * 64, wn = (wid & 1) * 64;
    const int sb = blockIdx.x;                    // col block (s), 0..63
    const int rb = blockIdx.y;                    // row block, 0..31
    f4 acc[4][4];
    #pragma unroll
    for (int i = 0; i < 4; ++i)
        #pragma unroll
        for (int j = 0; j < 4; ++j) acc[i][j] = (f4){0.f, 0.f, 0.f, 0.f};

    #pragma unroll
    for (int kc = 0; kc < 4; ++kc) {
        const size_t ta = (size_t)(rb * 4 + kc) * 8192;   // A tile bytes
        const size_t tb = (size_t)(sb * 4 + kc) * 8192;   // B tile bytes
        const int wo = wid * 2048 + lane * 16;
        glds16((const char*)C2h + ta + wo,        (char*)ah + wid * 2048);
        glds16((const char*)C2h + ta + wo + 1024, (char*)ah + wid * 2048 + 1024);
        glds16((const char*)C2l + ta + wo,        (char*)al + wid * 2048);
        glds16((const char*)C2l + ta + wo + 1024, (char*)al + wid * 2048 + 1024);
        glds16((const char*)T1h + tb + wo,        (char*)bh + wid * 2048);
        glds16((const char*)T1h + tb + wo + 1024, (char*)bh + wid * 2048 + 1024);
        glds16((const char*)T1l + tb + wo,        (char*)bl + wid * 2048);
        glds16((const char*)T1l + tb + wo + 1024, (char*)bl + wid * 2048 + 1024);
        __syncthreads();
        {
            const int kk = (lane >> 4) * 8;
            s8v Bh[4], Bl[4];
            #pragma unroll
            for (int nf = 0; nf < 4; ++nf) {
                int us = SW32(wn + nf * 16 + (lane & 15), kk);
                Bh[nf] = *(const s8v*)&bh[us];
                Bl[nf] = *(const s8v*)&bl[us];
            }
            #pragma unroll
            for (int mf = 0; mf < 4; ++mf) {
                int us = SW32(wm + mf * 16 + (lane & 15), kk);
                s8v Ah = *(const s8v*)&ah[us];
                s8v Al = *(const s8v*)&al[us];
                #pragma unroll
                for (int nf = 0; nf < 4; ++nf) {
                    acc[mf][nf] = __builtin_amdgcn_mfma_f32_16x16x32_bf16(Ah, Bh[nf], acc[mf][nf], 0, 0, 0);
                    acc[mf][nf] = __builtin_amdgcn_mfma_f32_16x16x32_bf16(Al, Bh[nf], acc[mf][nf], 0, 0, 0);
                    acc[mf][nf] = __builtin_amdgcn_mfma_f32_16x16x32_bf16(Ah, Bl[nf], acc[mf][nf], 0, 0, 0);
                }
            }
        }
        __syncthreads();
    }
    #pragma unroll
    for (int mf = 0; mf < 4; ++mf) {
        int rr = rb * 128 + wm + mf * 16 + (lane >> 4) * 4;
        #pragma unroll
        for (int nf = 0; nf < 4; ++nf) {
            int c = sb * 128 + wn + nf * 16 + (lane & 15);
            #pragma unroll
            for (int r = 0; r < 4; ++r)
                y[(size_t)(rr + r) * S_LEN + c] = acc[mf][nf][r];
        }
    }
}

extern "C" void kernel_launch(void* const* d_in, const int* in_sizes, int n_in,
                              void* d_out, int out_size, void* d_ws, size_t ws_size,
                              hipStream_t stream) {
    const float* x      = (const float*)d_in[0];
    const float* w_real = (const float*)d_in[1];
    const float* w_imag = (const float*)d_in[2];
    float* y = (float*)d_out;

    const size_t TBL = (size_t)S_LEN * 128;       // 1M ushort per table image
    char* w0 = (char*)d_ws;
    short* T1h = (short*)w0;                      // K3 basis image hi/lo
    short* T1l = T1h + TBL;
    short* T2h = T1l + TBL;                       // K1 basis image hi/lo
    short* T2l = T2h + TBL;
    float* X   = (float*)(T2l + TBL);             // 4096*128 fp32
    short* C2h = (short*)(X + (size_t)4096 * 128);// K3 A image hi/lo
    short* C2l = C2h + (size_t)4096 * 128;
    const size_t TOTAL = (size_t)((char*)(C2l + (size_t)4096 * 128) - w0);
    if (ws_size < TOTAL) {
        fprintf(stderr, "kernel_launch: ws too small (%zu < %zu bytes)\n", ws_size, TOTAL);
        return;
    }

    hipMemsetAsync(X, 0, (size_t)4096 * 128 * sizeof(float), stream);
    gen_t1_img<<<(S_LEN * 128) / 256, 256, 0, stream>>>(T1h, T1l);
    gen_t2_img<<<(S_LEN * 128) / 256, 256, 0, stream>>>(T2h, T2l);
    dft_fwd_mfma<<<dim3(4096 / 128, KSPLIT), 256, 0, stream>>>(x, T2h, T2l, X);
    mode_contract<<<dim3(NM, 4), 256, 0, stream>>>(X, w_real, w_imag, C2h, C2l);
    idft_mfma<<<dim3(S_LEN / 128, 4096 / 128), 256, 0, stream>>>(C2h, C2l, T1h, T1l, y);
}